// Round 1
// baseline (589.292 us; speedup 1.0000x reference)
//
#include <hip/hip_runtime.h>
#include <hip/hip_bf16.h>

#define C 128
#define HH 128
#define WW 128
#define L 16384
#define B 8
#define MID 32
#define NBL (B * L)

typedef __hip_bfloat16 bf16;

__device__ __forceinline__ float b2f(bf16 v) { return __bfloat162float(v); }

// ---------------------------------------------------------------- k_gap
__global__ __launch_bounds__(256) void k_gap(const float* __restrict__ x,
                                             float* __restrict__ gap) {
    int bc = blockIdx.x;  // b*128 + c
    const float4* p = (const float4*)(x + (size_t)bc * L);
    float s = 0.f;
    for (int i = threadIdx.x; i < L / 4; i += 256) {
        float4 v = p[i];
        s += (v.x + v.y) + (v.z + v.w);
    }
    __shared__ float red[256];
    red[threadIdx.x] = s;
    __syncthreads();
    for (int w = 128; w > 0; w >>= 1) {
        if (threadIdx.x < w) red[threadIdx.x] += red[threadIdx.x + w];
        __syncthreads();
    }
    if (threadIdx.x == 0) gap[bc] = red[0] * (1.f / (float)L);
}

// ---------------------------------------------------------------- k_prep_b
// per b: normalize gap -> g ; a[m] = w_mlp1 @ g ; gw[c'] = sum_o g[o]*Wco[o,c']
__global__ __launch_bounds__(128) void k_prep_b(const float* __restrict__ gap,
                                                const float* __restrict__ w_mlp1,
                                                const float* __restrict__ w_ch_out,
                                                float* __restrict__ g,
                                                float* __restrict__ a,
                                                float* __restrict__ gw) {
    int b = blockIdx.x, c = threadIdx.x;
    __shared__ float gl[C];
    __shared__ float red[C];
    float v = gap[b * C + c];
    red[c] = v * v;
    __syncthreads();
    for (int w = 64; w > 0; w >>= 1) {
        if (c < w) red[c] += red[c + w];
        __syncthreads();
    }
    float nrm = fmaxf(sqrtf(red[0]), 1e-12f);
    float gc = v / nrm;
    gl[c] = gc;
    g[b * C + c] = gc;
    __syncthreads();
    if (c < MID) {
        float s = 0.f;
        for (int k = 0; k < C; k++) s = fmaf(w_mlp1[c * C + k], gl[k], s);
        a[b * MID + c] = s;
    }
    {
        float s = 0.f;
        for (int k = 0; k < C; k++) s = fmaf(gl[k], w_ch_out[k * C + c], s);
        gw[b * C + c] = s;
    }
}

// ---------------------------------------------------------------- k_prep_w
// transposes + folded products. one block per output row o.
__global__ __launch_bounds__(128) void k_prep_w(const float* __restrict__ Win,
                                                const float* __restrict__ Wci,
                                                const float* __restrict__ Wproj,
                                                const float* __restrict__ Wout,
                                                const float* __restrict__ w_mlp2,
                                                const float* __restrict__ b_mlp2,
                                                float* __restrict__ WinT,
                                                float* __restrict__ WciT,
                                                float* __restrict__ WprojT,
                                                float* __restrict__ WpoT,
                                                float* __restrict__ W2pT,
                                                float* __restrict__ bp) {
    int o = blockIdx.x, c = threadIdx.x;
    __shared__ float pr[C];
    pr[c] = Wproj[o * C + c];
    __syncthreads();
    WinT[c * C + o] = Win[o * C + c];
    WciT[c * C + o] = Wci[o * C + c];
    WprojT[c * C + o] = pr[c];
    float s = 0.f;
    for (int k = 0; k < C; k++) s = fmaf(pr[k], Wout[k * C + c], s);
    WpoT[c * C + o] = s;
    if (c < MID) {
        float s2 = 0.f;
        for (int k = 0; k < C; k++) s2 = fmaf(pr[k], w_mlp2[k * MID + c], s2);
        W2pT[c * C + o] = s2;  // W2pT[m][o]
    }
    if (c == 0) {
        float s3 = 0.f;
        for (int k = 0; k < C; k++) s3 = fmaf(pr[k], b_mlp2[k], s3);
        bp[o] = s3;
    }
}

// ---------------------------------------------------------------- k_mm2
// t = Win @ x , u = Wci @ x for a tile of 64 positions. bf16 outputs.
__global__ __launch_bounds__(256) void k_mm2(const float* __restrict__ x,
                                             const float* __restrict__ WinT,
                                             const float* __restrict__ WciT,
                                             bf16* __restrict__ t_,
                                             bf16* __restrict__ u_) {
    __shared__ float xs[C][64];
    int b = blockIdx.x >> 8;
    int l0 = (blockIdx.x & 255) * 64;
    const int tid = threadIdx.x;
    // stage x tile (128 rows x 64 floats)
#pragma unroll
    for (int it = 0; it < 8; it++) {
        int f = tid + it * 256;  // float4 index 0..2047
        int row = f >> 4, col4 = f & 15;
        float4 v = *(const float4*)(x + (size_t)(b * C + row) * L + l0 + col4 * 4);
        *(float4*)(&xs[row][col4 * 4]) = v;
    }
    __syncthreads();
    int ot = tid >> 4, lt = tid & 15;
    int o0 = ot * 8, x0 = lt * 4;
    float acct[8][4], accu[8][4];
#pragma unroll
    for (int i = 0; i < 8; i++)
#pragma unroll
        for (int j = 0; j < 4; j++) { acct[i][j] = 0.f; accu[i][j] = 0.f; }
    for (int c = 0; c < C; c++) {
        float4 xv = *(const float4*)(&xs[c][x0]);
        float4 wa0 = *(const float4*)(WinT + c * C + o0);
        float4 wa1 = *(const float4*)(WinT + c * C + o0 + 4);
        float4 wb0 = *(const float4*)(WciT + c * C + o0);
        float4 wb1 = *(const float4*)(WciT + c * C + o0 + 4);
        float xa[4] = {xv.x, xv.y, xv.z, xv.w};
        float wa[8] = {wa0.x, wa0.y, wa0.z, wa0.w, wa1.x, wa1.y, wa1.z, wa1.w};
        float wb[8] = {wb0.x, wb0.y, wb0.z, wb0.w, wb1.x, wb1.y, wb1.z, wb1.w};
#pragma unroll
        for (int i = 0; i < 8; i++)
#pragma unroll
            for (int j = 0; j < 4; j++) {
                acct[i][j] = fmaf(wa[i], xa[j], acct[i][j]);
                accu[i][j] = fmaf(wb[i], xa[j], accu[i][j]);
            }
    }
#pragma unroll
    for (int i = 0; i < 8; i++) {
        size_t base = (size_t)(b * C + o0 + i) * L + l0 + x0;
        union { bf16 h[4]; uint2 q; } pt, pu;
#pragma unroll
        for (int j = 0; j < 4; j++) {
            pt.h[j] = __float2bfloat16(acct[i][j]);
            pu.h[j] = __float2bfloat16(accu[i][j]);
        }
        *(uint2*)(t_ + base) = pt.q;
        *(uint2*)(u_ + base) = pu.q;
    }
}

// ---------------------------------------------------------------- k_fused
// per (b, y, x-quarter of 32): stencil C(t) -> ctA ; dwconv(u) -> vB ;
// s1 = gw.v ; sil[m][x] = silu(a_m*s1+b1_m) ; vB <- y_diff ;
// out_pre = WpoT.ct + WprojT.ydiff + W2pT.sil + bp ; per-channel stats atomics.
__global__ __launch_bounds__(256) void k_fused(
    const float* __restrict__ x, const bf16* __restrict__ t_, const bf16* __restrict__ u_,
    const float* __restrict__ wds, const float* __restrict__ wcd,
    const float* __restrict__ gw, const float* __restrict__ aa, const float* __restrict__ b1,
    const float* __restrict__ WpoT, const float* __restrict__ WprojT,
    const float* __restrict__ W2pT, const float* __restrict__ bp,
    const float* __restrict__ p_dw, float* __restrict__ outp, float* __restrict__ stats) {
    __shared__ float ctA[C][32];
    __shared__ float vB[C][32];
    __shared__ float sil[MID][32];
    __shared__ float s1l[32];
    __shared__ float gwl[C];
    __shared__ float al[MID], b1l[MID];

    const int tid = threadIdx.x;
    const int bid = blockIdx.x;  // 4096
    const int b = bid >> 9;
    const int rem = bid & 511;
    const int y = rem >> 2;
    const int xq = rem & 3;
    const int xbase = xq * 32;
    const int l0 = y * WW + xbase;

    if (tid < C) gwl[tid] = gw[b * C + tid];
    else if (tid < C + MID) {
        int m = tid - C;
        al[m] = aa[b * MID + m];
        b1l[m] = b1[m];
    }
    // -------- stage 1: ct and v
    {
        int xl = tid & 31;
        int cg = tid >> 5;  // 0..7
        int xg = xbase + xl;
        int l = l0 + xl;
        for (int ci = 0; ci < 16; ci++) {
            int c = cg * 16 + ci;
            const bf16* tb = t_ + (size_t)(b * C + c) * L;
            float kw0 = wds[c * 3 + 0], kw1 = wds[c * 3 + 1], kw2 = wds[c * 3 + 2];
            float kwS = 0.25f * (kw0 + kw2);
            float tc = b2f(tb[l]);
            int ip = (l > 0) ? l - 1 : 0;
            float trp = b2f(tb[ip]);
            trp = (l > 0) ? trp : 0.f;
            int in_ = (l < L - 1) ? l + 1 : l;
            float trn = b2f(tb[in_]);
            trn = (l < L - 1) ? trn : 0.f;
            float tcp, tcn;
            if (y > 0) tcp = b2f(tb[l - WW]);
            else {
                int idx = (xg > 0) ? ((HH - 1) * WW + xg - 1) : 0;
                tcp = b2f(tb[idx]);
                tcp = (xg > 0) ? tcp : 0.f;
            }
            if (y < HH - 1) tcn = b2f(tb[l + WW]);
            else {
                int idx = (xg < WW - 1) ? (xg + 1) : 0;
                tcn = b2f(tb[idx]);
                tcn = (xg < WW - 1) ? tcn : 0.f;
            }
            ctA[c][xl] = kwS * ((trp + trn) + (tcp + tcn)) + kw1 * tc;

            const bf16* ub = u_ + (size_t)(b * C + c) * L;
            float kd0 = wcd[c * 3 + 0], kd1 = wcd[c * 3 + 1], kd2 = wcd[c * 3 + 2];
            float uc = b2f(ub[l]);
            float up = b2f(ub[ip]);
            up = (l > 0) ? up : 0.f;
            float un = b2f(ub[in_]);
            un = (l < L - 1) ? un : 0.f;
            vB[c][xl] = kd0 * up + kd1 * uc + kd2 * un;
        }
    }
    __syncthreads();
    // -------- stage 1b: s1
    if (tid < 32) {
        float s = 0.f;
        for (int c = 0; c < C; c++) s = fmaf(gwl[c], vB[c][tid], s);
        s1l[tid] = s;
    }
    __syncthreads();
    // -------- stage 1c: sil + y_diff overwrites vB
    {
        int m = tid >> 3;
        int xs0 = (tid & 7) * 4;
#pragma unroll
        for (int j = 0; j < 4; j++) {
            int xx = xs0 + j;
            float pre = fmaf(al[m], s1l[xx], b1l[m]);
            sil[m][xx] = pre / (1.f + __expf(-pre));
        }
    }
    {
        const float dwt = p_dw[0] * 0.25f;
        int xl = tid & 31;
        int cg = tid >> 5;
        int xg = xbase + xl;
        for (int ci = 0; ci < 16; ci++) {
            int c = cg * 16 + ci;
            const float* xb = x + (size_t)(b * C + c) * L + (size_t)y * WW;
            float cen = xb[xg];
            float lf = xb[(xg >= 1) ? (xg - 1) : 1];
            float rt = xb[(xg <= WW - 2) ? (xg + 1) : (WW - 2)];
            const float* xu = x + (size_t)(b * C + c) * L + (size_t)((y >= 1) ? (y - 1) : 1) * WW;
            const float* xd = x + (size_t)(b * C + c) * L + (size_t)((y <= HH - 2) ? (y + 1) : (HH - 2)) * WW;
            float diff = fabsf(cen - lf) + fabsf(cen - rt) + fabsf(cen - xu[xg]) + fabsf(cen - xd[xg]);
            vB[c][xl] = fmaf(dwt, diff, cen);
        }
    }
    __syncthreads();
    // -------- stage 2: fused output matmul
    int ot = tid >> 3, xt = tid & 7;
    int o0 = ot * 4, x0 = xt * 4;
    float acc[4][4];
#pragma unroll
    for (int i = 0; i < 4; i++)
#pragma unroll
        for (int j = 0; j < 4; j++) acc[i][j] = 0.f;
    for (int c = 0; c < C; c++) {
        float4 cv = *(const float4*)(&ctA[c][x0]);
        float4 dv = *(const float4*)(&vB[c][x0]);
        float4 wo = *(const float4*)(WpoT + c * C + o0);
        float4 wp = *(const float4*)(WprojT + c * C + o0);
        float cva[4] = {cv.x, cv.y, cv.z, cv.w};
        float dva[4] = {dv.x, dv.y, dv.z, dv.w};
        float woa[4] = {wo.x, wo.y, wo.z, wo.w};
        float wpa[4] = {wp.x, wp.y, wp.z, wp.w};
#pragma unroll
        for (int i = 0; i < 4; i++)
#pragma unroll
            for (int j = 0; j < 4; j++)
                acc[i][j] = fmaf(woa[i], cva[j], fmaf(wpa[i], dva[j], acc[i][j]));
    }
    for (int m = 0; m < MID; m++) {
        float4 sv = *(const float4*)(&sil[m][x0]);
        float4 w2 = *(const float4*)(W2pT + m * C + o0);
        float sva[4] = {sv.x, sv.y, sv.z, sv.w};
        float w2a[4] = {w2.x, w2.y, w2.z, w2.w};
#pragma unroll
        for (int i = 0; i < 4; i++)
#pragma unroll
            for (int j = 0; j < 4; j++) acc[i][j] = fmaf(w2a[i], sva[j], acc[i][j]);
    }
    float4 bpv = *(const float4*)(bp + o0);
    float bpa[4] = {bpv.x, bpv.y, bpv.z, bpv.w};
    float rs[4], rq[4];
#pragma unroll
    for (int i = 0; i < 4; i++) {
        rs[i] = 0.f;
        rq[i] = 0.f;
#pragma unroll
        for (int j = 0; j < 4; j++) {
            acc[i][j] += bpa[i];
            rs[i] += acc[i][j];
            rq[i] = fmaf(acc[i][j], acc[i][j], rq[i]);
        }
        size_t base = (size_t)(b * C + o0 + i) * L + l0 + x0;
        *(float4*)(outp + base) = make_float4(acc[i][0], acc[i][1], acc[i][2], acc[i][3]);
    }
    __syncthreads();  // everyone done reading ctA
    float* red = &ctA[0][0];    // 1024 floats
    float* redq = red + 1024;   // 1024 floats (still inside ctA)
#pragma unroll
    for (int i = 0; i < 4; i++) {
        red[(o0 + i) * 8 + xt] = rs[i];
        redq[(o0 + i) * 8 + xt] = rq[i];
    }
    __syncthreads();
    if (tid < C) {
        float s = 0.f, q = 0.f;
#pragma unroll
        for (int k = 0; k < 8; k++) {
            s += red[tid * 8 + k];
            q += redq[tid * 8 + k];
        }
        atomicAdd(&stats[tid], s);
        atomicAdd(&stats[C + tid], q);
    }
}

// ---------------------------------------------------------------- BN
__global__ void k_bnstats(const float* __restrict__ stats, const float* __restrict__ gamma,
                          const float* __restrict__ beta, float* __restrict__ scsh) {
    int o = threadIdx.x;
    float n = (float)NBL;
    float mu = stats[o] / n;
    float var = stats[C + o] / n - mu * mu;
    float sc = gamma[o] * rsqrtf(var + 1e-5f);
    scsh[o] = sc;
    scsh[C + o] = fmaf(-mu, sc, beta[o]);
}

__global__ __launch_bounds__(256) void k_bnapply(float* __restrict__ outp,
                                                 const float* __restrict__ scsh) {
    int bo = blockIdx.x;  // 1024
    int o = bo & (C - 1);
    float sc = scsh[o], sh = scsh[C + o];
    float4* p = (float4*)(outp + (size_t)bo * L);
    for (int i = threadIdx.x; i < L / 4; i += 256) {
        float4 v = p[i];
        v.x = fmaf(v.x, sc, sh);
        v.y = fmaf(v.y, sc, sh);
        v.z = fmaf(v.z, sc, sh);
        v.w = fmaf(v.w, sc, sh);
        p[i] = v;
    }
}

// ---------------------------------------------------------------- launch
extern "C" void kernel_launch(void* const* d_in, const int* in_sizes, int n_in,
                              void* d_out, int out_size, void* d_ws, size_t ws_size,
                              hipStream_t stream) {
    const float* x = (const float*)d_in[0];
    const float* Win = (const float*)d_in[1];
    const float* wds = (const float*)d_in[2];
    const float* Wout = (const float*)d_in[3];
    const float* Wci = (const float*)d_in[4];
    const float* wcd = (const float*)d_in[5];
    const float* Wco = (const float*)d_in[6];
    const float* w1 = (const float*)d_in[7];
    const float* b1 = (const float*)d_in[8];
    const float* w2 = (const float*)d_in[9];
    const float* b2 = (const float*)d_in[10];
    const float* pdw = (const float*)d_in[11];
    const float* gamma = (const float*)d_in[12];
    const float* beta = (const float*)d_in[13];
    const float* Wproj = (const float*)d_in[14];

    char* wsb = (char*)d_ws;
    bf16* t_ = (bf16*)wsb;                          // 33.55 MB
    bf16* u_ = (bf16*)(wsb + 33554432);             // 33.55 MB
    float* gap = (float*)(wsb + 67108864);
    float* g = gap + 1024;
    float* a = g + 1024;
    float* gw = a + 256;
    float* WinT = gw + 1024;
    float* WciT = WinT + 16384;
    float* WprojT = WciT + 16384;
    float* WpoT = WprojT + 16384;
    float* W2pT = WpoT + 16384;
    float* bp = W2pT + 4096;
    float* stats = bp + 128;
    float* scsh = stats + 256;
    float* outp = (float*)d_out;

    hipMemsetAsync(stats, 0, 256 * sizeof(float), stream);
    k_gap<<<1024, 256, 0, stream>>>(x, gap);
    k_prep_b<<<8, 128, 0, stream>>>(gap, w1, Wco, g, a, gw);
    k_prep_w<<<128, 128, 0, stream>>>(Win, Wci, Wproj, Wout, w2, b2,
                                      WinT, WciT, WprojT, WpoT, W2pT, bp);
    k_mm2<<<2048, 256, 0, stream>>>(x, WinT, WciT, t_, u_);
    k_fused<<<4096, 256, 0, stream>>>(x, t_, u_, wds, wcd, gw, a, b1,
                                      WpoT, WprojT, W2pT, bp, pdw, outp, stats);
    k_bnstats<<<1, 128, 0, stream>>>(stats, gamma, beta, scsh);
    k_bnapply<<<1024, 256, 0, stream>>>(outp, scsh);
}

// Round 3
// 313.905 us; speedup vs baseline: 1.8773x; 1.8773x over previous
//
#include <hip/hip_runtime.h>
#include <hip/hip_bf16.h>

#define C 128
#define L 16384
#define B 8
#define MID 32
#define NBL (B * L)

typedef unsigned short ushort_t;
typedef __attribute__((ext_vector_type(8))) short s8v;   // 8 bf16
typedef __attribute__((ext_vector_type(4))) float f4v;   // 4 fp32

__device__ __forceinline__ unsigned short f2bf(float f) {
    union { float f; unsigned int u; } a; a.f = f;
    unsigned int u = a.u;
    return (unsigned short)((u + 0x7fffu + ((u >> 16) & 1u)) >> 16);
}

__device__ __forceinline__ void load8(const ushort_t* p, float* f) {
    uint4 u = *(const uint4*)p;
    f[0] = __uint_as_float(u.x << 16); f[1] = __uint_as_float(u.x & 0xffff0000u);
    f[2] = __uint_as_float(u.y << 16); f[3] = __uint_as_float(u.y & 0xffff0000u);
    f[4] = __uint_as_float(u.z << 16); f[5] = __uint_as_float(u.z & 0xffff0000u);
    f[6] = __uint_as_float(u.w << 16); f[7] = __uint_as_float(u.w & 0xffff0000u);
}

__device__ __forceinline__ void zero8(float* f) {
#pragma unroll
    for (int j = 0; j < 8; j++) f[j] = 0.f;
}

__device__ __forceinline__ void store8(ushort_t* p, const float* f) {
    union { ushort_t h[8]; uint4 q; } u;
#pragma unroll
    for (int j = 0; j < 8; j++) u.h[j] = f2bf(f[j]);
    *(uint4*)p = u.q;
}

__device__ __forceinline__ void ld8f(const float* p, float* f) {
    float4 a = *(const float4*)p;
    float4 b = *(const float4*)(p + 4);
    f[0] = a.x; f[1] = a.y; f[2] = a.z; f[3] = a.w;
    f[4] = b.x; f[5] = b.y; f[6] = b.z; f[7] = b.w;
}

// ------------------------------------------------ k_cvt: x fp32 [b][c][l] -> xb_t bf16 [b][l][c], + gap sums
__global__ __launch_bounds__(256) void k_cvt(const float* __restrict__ x,
                                             ushort_t* __restrict__ xb,
                                             float* __restrict__ gap) {
    __shared__ float xs[64][129];
    const int bid = blockIdx.x;
    const int b = bid >> 8;
    const int l0 = (bid & 255) * 64;
    const int tid = threadIdx.x;
    const int c = tid >> 1, h = tid & 1;
    const float* src = x + ((size_t)(b * C + c)) * L + l0 + h * 32;
    float s = 0.f;
#pragma unroll
    for (int j = 0; j < 8; j++) {
        float4 v = *(const float4*)(src + j * 4);
        s += (v.x + v.y) + (v.z + v.w);
        int lb = h * 32 + j * 4;
        xs[lb + 0][c] = v.x; xs[lb + 1][c] = v.y;
        xs[lb + 2][c] = v.z; xs[lb + 3][c] = v.w;
    }
    s += __shfl_xor(s, 1);
    if (h == 0) atomicAdd(&gap[b * C + c], s);
    __syncthreads();
    const int l = tid & 63, quarter = tid >> 6, cb = quarter * 32;
    union { ushort_t hh[32]; uint4 q[4]; } u;
#pragma unroll
    for (int k = 0; k < 32; k++) u.hh[k] = f2bf(xs[l][cb + k]);
    uint4* dst = (uint4*)(xb + ((size_t)(b * L + l0 + l)) * C + cb);
#pragma unroll
    for (int k = 0; k < 4; k++) dst[k] = u.q[k];
}

// ------------------------------------------------ k_prep_b
__global__ __launch_bounds__(128) void k_prep_b(const float* __restrict__ gap,
                                                const float* __restrict__ w1,
                                                const float* __restrict__ Wco,
                                                float* __restrict__ a,
                                                float* __restrict__ gw) {
    int b = blockIdx.x, c = threadIdx.x;
    __shared__ float gl[C];
    __shared__ float red[C];
    float v = gap[b * C + c] * (1.f / (float)L);
    red[c] = v * v;
    __syncthreads();
    for (int w = 64; w > 0; w >>= 1) {
        if (c < w) red[c] += red[c + w];
        __syncthreads();
    }
    float nrm = fmaxf(sqrtf(red[0]), 1e-12f);
    float gc = v / nrm;
    gl[c] = gc;
    __syncthreads();
    if (c < MID) {
        float s = 0.f;
        for (int k = 0; k < C; k++) s = fmaf(w1[c * C + k], gl[k], s);
        a[b * MID + c] = s;
    }
    {
        float s = 0.f;
        for (int k = 0; k < C; k++) s = fmaf(gl[k], Wco[k * C + c], s);
        gw[b * C + c] = s;
    }
}

// ------------------------------------------------ k_prep_w
__global__ __launch_bounds__(128) void k_prep_w(const float* __restrict__ Win,
                                                const float* __restrict__ Wci,
                                                const float* __restrict__ Wproj,
                                                const float* __restrict__ Wout,
                                                const float* __restrict__ w2,
                                                const float* __restrict__ b2,
                                                const float* __restrict__ wds,
                                                const float* __restrict__ wcd,
                                                ushort_t* __restrict__ Wio,
                                                ushort_t* __restrict__ Wcat,
                                                float* __restrict__ bp,
                                                float* __restrict__ kwS,
                                                float* __restrict__ kw1,
                                                float* __restrict__ kd0,
                                                float* __restrict__ kd1,
                                                float* __restrict__ kd2) {
    int o = blockIdx.x, c = threadIdx.x;
    __shared__ float pr[C];
    pr[c] = Wproj[o * C + c];
    __syncthreads();
    Wio[o * C + c] = f2bf(Win[o * C + c]);
    Wio[(C + o) * C + c] = f2bf(Wci[o * C + c]);
    float s = 0.f;
    for (int k = 0; k < C; k++) s = fmaf(pr[k], Wout[k * C + c], s);
    Wcat[o * 288 + c] = f2bf(s);
    Wcat[o * 288 + 128 + c] = f2bf(pr[c]);
    if (c < MID) {
        float s2 = 0.f;
        for (int k = 0; k < C; k++) s2 = fmaf(pr[k], w2[k * MID + c], s2);
        Wcat[o * 288 + 256 + c] = f2bf(s2);
    }
    if (c == 0) {
        float s3 = 0.f;
        for (int k = 0; k < C; k++) s3 = fmaf(pr[k], b2[k], s3);
        bp[o] = s3;
    }
    if (o == 0) {
        kwS[c] = 0.25f * (wds[3 * c] + wds[3 * c + 2]);
        kw1[c] = wds[3 * c + 1];
        kd0[c] = wcd[3 * c];
        kd1[c] = wcd[3 * c + 1];
        kd2[c] = wcd[3 * c + 2];
    }
}

// ------------------------------------------------ k_gemm1: tu_t[l][0:256] = [Win;Wci] @ x  (MFMA)
__global__ __launch_bounds__(512, 1) void k_gemm1(const ushort_t* __restrict__ xb,
                                                  const ushort_t* __restrict__ Wio,
                                                  ushort_t* __restrict__ tu) {
    __shared__ ushort_t wl[128 * 136];
    const int tid = threadIdx.x;
    const int bid = blockIdx.x;               // 8 b * 2 ms * 128 lt
    const int b = bid >> 8;
    const int ms = (bid >> 7) & 1;
    const int lt = bid & 127;
    {
        int row = tid >> 2, qq = tid & 3;     // 128 rows, 32-ushort chunk each
        const uint4* s4 = (const uint4*)(Wio + (ms * C + row) * C + qq * 32);
        uint4* d4 = (uint4*)(wl + row * 136 + qq * 32);
        d4[0] = s4[0]; d4[1] = s4[1]; d4[2] = s4[2]; d4[3] = s4[3];
    }
    __syncthreads();
    const int wave = tid >> 6, lane = tid & 63;
    const int l0 = lt * 128 + wave * 16;
    const int n = lane & 15, q = lane >> 4;
    const ushort_t* brow = xb + ((size_t)(b * L + l0 + n)) * C + q * 8;
    s8v bfrag[4];
#pragma unroll
    for (int ks = 0; ks < 4; ks++) bfrag[ks] = *(const s8v*)(brow + ks * 32);
    f4v acc[8];
#pragma unroll
    for (int i = 0; i < 8; i++) acc[i] = (f4v){0.f, 0.f, 0.f, 0.f};
#pragma unroll
    for (int ks = 0; ks < 4; ks++) {
#pragma unroll
        for (int mt = 0; mt < 8; mt++) {
            s8v af = *(const s8v*)(wl + (mt * 16 + n) * 136 + ks * 32 + q * 8);
            acc[mt] = __builtin_amdgcn_mfma_f32_16x16x32_bf16(af, bfrag[ks], acc[mt], 0, 0, 0);
        }
    }
    ushort_t* orow = tu + ((size_t)(b * L + l0 + n)) * 256 + ms * C + q * 4;
#pragma unroll
    for (int mt = 0; mt < 8; mt++) {
        union { ushort_t h[4]; uint2 q2; } u;
#pragma unroll
        for (int i = 0; i < 4; i++) u.h[i] = f2bf(acc[mt][i]);
        *(uint2*)(orow + mt * 16) = u.q2;
    }
}

// ------------------------------------------------ k_mid: stencils + silu -> Kbuf[l][288]
__global__ __launch_bounds__(256) void k_mid(const ushort_t* __restrict__ tu,
                                             const ushort_t* __restrict__ xb,
                                             const float* __restrict__ kwS,
                                             const float* __restrict__ kw1,
                                             const float* __restrict__ kd0,
                                             const float* __restrict__ kd1,
                                             const float* __restrict__ kd2,
                                             const float* __restrict__ gw,
                                             const float* __restrict__ a,
                                             const float* __restrict__ b1,
                                             const float* __restrict__ pdw,
                                             ushort_t* __restrict__ Kb) {
    const int tid = threadIdx.x;
    const int cc = tid & 15, p = tid >> 4;
    const int bid = blockIdx.x;
    const int b = bid >> 10;
    const int l = (bid & 1023) * 16 + p;
    const int y = l >> 7, xg = l & 127;
    const int c0 = cc * 8;
    const size_t rb = (size_t)b * L;

    const int rL = (l > 0) ? (l - 1) : -1;
    const int rR = (l < L - 1) ? (l + 1) : -1;
    const int rU = (y > 0) ? (l - 128) : ((xg > 0) ? (16256 + xg - 1) : -1);
    const int rD = (y < 127) ? (l + 128) : ((xg < 127) ? (xg + 1) : -1);
    const int sL = (xg > 0) ? (l - 1) : (l + 1);
    const int sR = (xg < 127) ? (l + 1) : (l - 1);
    const int sU = (y > 0) ? (l - 128) : (l + 128);
    const int sD = (y < 127) ? (l + 128) : (l - 128);

    float tC[8], tLe[8], tRi[8], tUp[8], tDo[8];
    load8(tu + (rb + l) * 256 + c0, tC);
    if (rL >= 0) load8(tu + (rb + rL) * 256 + c0, tLe); else zero8(tLe);
    if (rR >= 0) load8(tu + (rb + rR) * 256 + c0, tRi); else zero8(tRi);
    if (rU >= 0) load8(tu + (rb + rU) * 256 + c0, tUp); else zero8(tUp);
    if (rD >= 0) load8(tu + (rb + rD) * 256 + c0, tDo); else zero8(tDo);

    float uC[8], uL8[8], uR8[8];
    load8(tu + (rb + l) * 256 + 128 + c0, uC);
    if (rL >= 0) load8(tu + (rb + rL) * 256 + 128 + c0, uL8); else zero8(uL8);
    if (rR >= 0) load8(tu + (rb + rR) * 256 + 128 + c0, uR8); else zero8(uR8);

    float xC[8], xL8[8], xR8[8], xU8[8], xD8[8];
    load8(xb + (rb + l) * C + c0, xC);
    load8(xb + (rb + sL) * C + c0, xL8);
    load8(xb + (rb + sR) * C + c0, xR8);
    load8(xb + (rb + sU) * C + c0, xU8);
    load8(xb + (rb + sD) * C + c0, xD8);

    float kS[8], k1[8], d0[8], d1[8], d2[8], gv[8];
    ld8f(kwS + c0, kS); ld8f(kw1 + c0, k1);
    ld8f(kd0 + c0, d0); ld8f(kd1 + c0, d1); ld8f(kd2 + c0, d2);
    ld8f(gw + b * C + c0, gv);
    const float dwt = pdw[0] * 0.25f;

    float ct[8], yd[8];
    float s1 = 0.f;
#pragma unroll
    for (int j = 0; j < 8; j++) {
        ct[j] = kS[j] * ((tLe[j] + tRi[j]) + (tUp[j] + tDo[j])) + k1[j] * tC[j];
        float vv = d0[j] * uL8[j] + d1[j] * uC[j] + d2[j] * uR8[j];
        s1 = fmaf(gv[j], vv, s1);
        float cen = xC[j];
        float d = fabsf(cen - xL8[j]) + fabsf(cen - xR8[j]) +
                  fabsf(cen - xU8[j]) + fabsf(cen - xD8[j]);
        yd[j] = fmaf(dwt, d, cen);
    }
    s1 += __shfl_xor(s1, 1);
    s1 += __shfl_xor(s1, 2);
    s1 += __shfl_xor(s1, 4);
    s1 += __shfl_xor(s1, 8);

    ushort_t* kr = Kb + (rb + l) * 288;
    store8(kr + c0, ct);
    store8(kr + 128 + c0, yd);
    if (cc < 4) {
        float av[8], bv[8], sv[8];
        ld8f(a + b * MID + cc * 8, av);
        ld8f(b1 + cc * 8, bv);
#pragma unroll
        for (int j = 0; j < 8; j++) {
            float pre = fmaf(av[j], s1, bv[j]);
            sv[j] = pre / (1.f + __expf(-pre));
        }
        store8(kr + 256 + cc * 8, sv);
    }
}

// ------------------------------------------------ k_gemm2: out = Wcat @ Kbuf + bp  (MFMA)
__global__ __launch_bounds__(512, 1) void k_gemm2(const ushort_t* __restrict__ Kb,
                                                  const ushort_t* __restrict__ Wcat,
                                                  const float* __restrict__ bp,
                                                  float* __restrict__ outp) {
    __shared__ ushort_t wl[64 * 296];
    const int tid = threadIdx.x;
    const int bid = blockIdx.x;               // 8 b * 2 ms * 128 lt
    const int b = bid >> 8;
    const int ms = (bid >> 7) & 1;
    const int lt = bid & 127;
    for (int i = 0; i < 5; i++) {
        int idx = tid + i * 512;              // uint4 index, total 2304
        if (idx < 2304) {
            int row = idx / 36, col = idx - row * 36;
            *(uint4*)(wl + row * 296 + col * 8) =
                *(const uint4*)(Wcat + (ms * 64 + row) * 288 + col * 8);
        }
    }
    __syncthreads();
    const int wave = tid >> 6, lane = tid & 63;
    const int l0 = lt * 128 + wave * 16;
    const int n = lane & 15, q = lane >> 4;
    const ushort_t* brow = Kb + ((size_t)(b * L + l0 + n)) * 288 + q * 8;
    f4v acc[4];
#pragma unroll
    for (int i = 0; i < 4; i++) acc[i] = (f4v){0.f, 0.f, 0.f, 0.f};
#pragma unroll
    for (int ks = 0; ks < 9; ks++) {
        s8v bf_ = *(const s8v*)(brow + ks * 32);
#pragma unroll
        for (int mt = 0; mt < 4; mt++) {
            s8v af = *(const s8v*)(wl + (mt * 16 + n) * 296 + ks * 32 + q * 8);
            acc[mt] = __builtin_amdgcn_mfma_f32_16x16x32_bf16(af, bf_, acc[mt], 0, 0, 0);
        }
    }
#pragma unroll
    for (int mt = 0; mt < 4; mt++) {
        int o0 = ms * 64 + mt * 16 + q * 4;
        float4 bv = *(const float4*)(bp + o0);
        float ba[4] = {bv.x, bv.y, bv.z, bv.w};
#pragma unroll
        for (int i = 0; i < 4; i++) {
            outp[((size_t)(b * C + o0 + i)) * L + l0 + n] = acc[mt][i] + ba[i];
        }
    }
}

// ------------------------------------------------ BN
__global__ __launch_bounds__(256) void k_bnstats2(const float* __restrict__ outp,
                                                  float* __restrict__ stats) {
    const int bo = blockIdx.x;
    const int o = bo & (C - 1);
    const float4* p = (const float4*)(outp + (size_t)bo * L);
    float s = 0.f, sq = 0.f;
    for (int i = threadIdx.x; i < L / 4; i += 256) {
        float4 v = p[i];
        s += (v.x + v.y) + (v.z + v.w);
        sq += v.x * v.x + v.y * v.y + v.z * v.z + v.w * v.w;
    }
    __shared__ float rs[256], rq[256];
    rs[threadIdx.x] = s; rq[threadIdx.x] = sq;
    __syncthreads();
    for (int w = 128; w > 0; w >>= 1) {
        if (threadIdx.x < w) {
            rs[threadIdx.x] += rs[threadIdx.x + w];
            rq[threadIdx.x] += rq[threadIdx.x + w];
        }
        __syncthreads();
    }
    if (threadIdx.x == 0) {
        atomicAdd(&stats[o], rs[0]);
        atomicAdd(&stats[C + o], rq[0]);
    }
}

__global__ void k_bnfin(const float* __restrict__ stats, const float* __restrict__ gamma,
                        const float* __restrict__ beta, float* __restrict__ scsh) {
    int o = threadIdx.x;
    float n = (float)NBL;
    float mu = stats[o] / n;
    float var = stats[C + o] / n - mu * mu;
    float sc = gamma[o] * rsqrtf(var + 1e-5f);
    scsh[o] = sc;
    scsh[C + o] = fmaf(-mu, sc, beta[o]);
}

__global__ __launch_bounds__(256) void k_bnapply(float* __restrict__ outp,
                                                 const float* __restrict__ scsh) {
    int bo = blockIdx.x;
    int o = bo & (C - 1);
    float sc = scsh[o], sh = scsh[C + o];
    float4* p = (float4*)(outp + (size_t)bo * L);
    for (int i = threadIdx.x; i < L / 4; i += 256) {
        float4 v = p[i];
        v.x = fmaf(v.x, sc, sh);
        v.y = fmaf(v.y, sc, sh);
        v.z = fmaf(v.z, sc, sh);
        v.w = fmaf(v.w, sc, sh);
        p[i] = v;
    }
}

// ------------------------------------------------ launch
extern "C" void kernel_launch(void* const* d_in, const int* in_sizes, int n_in,
                              void* d_out, int out_size, void* d_ws, size_t ws_size,
                              hipStream_t stream) {
    const float* x = (const float*)d_in[0];
    const float* Win = (const float*)d_in[1];
    const float* wds = (const float*)d_in[2];
    const float* Wout = (const float*)d_in[3];
    const float* Wci = (const float*)d_in[4];
    const float* wcd = (const float*)d_in[5];
    const float* Wco = (const float*)d_in[6];
    const float* w1 = (const float*)d_in[7];
    const float* b1 = (const float*)d_in[8];
    const float* w2 = (const float*)d_in[9];
    const float* b2 = (const float*)d_in[10];
    const float* pdw = (const float*)d_in[11];
    const float* gamma = (const float*)d_in[12];
    const float* beta = (const float*)d_in[13];
    const float* Wproj = (const float*)d_in[14];

    char* wsb = (char*)d_ws;
    ushort_t* xb = (ushort_t*)wsb;                       // 33,554,432 B
    ushort_t* tu = (ushort_t*)(wsb + 33554432);          // 67,108,864 B
    ushort_t* Kb = (ushort_t*)(wsb + 100663296);         // 75,497,472 B
    char* S = wsb + 176160768;
    float* gap  = (float*)(S + 0);        // 1024
    float* stats= (float*)(S + 4096);     // 256
    float* scsh = (float*)(S + 5120);     // 256
    float* a    = (float*)(S + 6144);     // 256
    float* gw   = (float*)(S + 7168);     // 1024
    float* bp   = (float*)(S + 11264);    // 128
    float* kwS  = (float*)(S + 11776);
    float* kw1  = (float*)(S + 12288);
    float* kd0  = (float*)(S + 12800);
    float* kd1  = (float*)(S + 13312);
    float* kd2  = (float*)(S + 13824);
    ushort_t* Wio  = (ushort_t*)(S + 14336);   // 65,536 B
    ushort_t* Wcat = (ushort_t*)(S + 79872);   // 73,728 B
    float* outp = (float*)d_out;

    hipMemsetAsync(S, 0, 5120, stream);  // gap + stats
    k_cvt<<<2048, 256, 0, stream>>>(x, xb, gap);
    k_prep_b<<<8, 128, 0, stream>>>(gap, w1, Wco, a, gw);
    k_prep_w<<<128, 128, 0, stream>>>(Win, Wci, Wproj, Wout, w2, b2, wds, wcd,
                                      Wio, Wcat, bp, kwS, kw1, kd0, kd1, kd2);
    k_gemm1<<<2048, 512, 0, stream>>>(xb, Wio, tu);
    k_mid<<<8192, 256, 0, stream>>>(tu, xb, kwS, kw1, kd0, kd1, kd2, gw, a, b1, pdw, Kb);
    k_gemm2<<<2048, 512, 0, stream>>>(Kb, Wcat, bp, outp);
    k_bnstats2<<<1024, 256, 0, stream>>>(outp, stats);
    k_bnfin<<<1, 128, 0, stream>>>(stats, gamma, beta, scsh);
    k_bnapply<<<1024, 256, 0, stream>>>(outp, scsh);
}